// Round 10
// baseline (170.243 us; speedup 1.0000x reference)
//
#include <hip/hip_runtime.h>

typedef __attribute__((ext_vector_type(8))) short short8;
typedef __attribute__((ext_vector_type(4))) short short4v;
typedef __attribute__((ext_vector_type(4))) float f32x4;
typedef __attribute__((ext_vector_type(2))) unsigned int uint2v;
typedef __attribute__((ext_vector_type(4))) unsigned int uint4v;

#define LOG2E 1.44269504088896340736f

__device__ __forceinline__ float fexp2(float v){ return __builtin_amdgcn_exp2f(v); }
__device__ __forceinline__ float frcp(float v){ return __builtin_amdgcn_rcpf(v); }
__device__ __forceinline__ float silu_f(float v){ return v * frcp(1.0f + fexp2(-v*LOG2E)); }
__device__ __forceinline__ float tanh_f(float v){ return 2.0f*frcp(1.0f+fexp2(-2.0f*LOG2E*v)) - 1.0f; }

__device__ __forceinline__ unsigned short f2bf(float f){
    unsigned int u = __float_as_uint(f);
    u = (u + 0x7FFFu + ((u>>16)&1u)) >> 16;
    return (unsigned short)u;
}
// v_cvt_pk_bf16_f32: lo16 = bf16(a), hi16 = bf16(b)
__device__ __forceinline__ unsigned int cvt_pk(float a, float b){
    unsigned int r;
    asm("v_cvt_pk_bf16_f32 %0, %1, %2" : "=v"(r) : "v"(a), "v"(b));
    return r;
}
__device__ __forceinline__ short4v mk4(unsigned int u0, unsigned int u1){
    uint2v t; t[0] = u0; t[1] = u1;
    return __builtin_bit_cast(short4v, t);
}
__device__ __forceinline__ short8 mk8(unsigned int a, unsigned int b, unsigned int c, unsigned int d){
    uint4v t; t[0] = a; t[1] = b; t[2] = c; t[3] = d;
    return __builtin_bit_cast(short8, t);
}

#define MFMA32(a,b,c) __builtin_amdgcn_mfma_f32_16x16x32_bf16(a,b,c,0,0,0)
#define MFMA16(a,b,c) __builtin_amdgcn_mfma_f32_16x16x16bf16_1k(a,b,c,0,0,0)

// Fragment layouts (validated rounds 2-9):
//  A frag: m=lane&15,  k = KW*(lane>>4)+e   (KW=8 for x32, 4 for x16)
//  B frag: n=lane&15,  k = KW*(lane>>4)+e
//  C frag: n=lane&15,  m = 4*(lane>>4)+r
//
// Layout tricks (R9, kept):
//  - gate A replicated: row m holds Wg2[:, m%4] (m%4<3) -> every lane's C
//    holds its row's 3 logits; no logit-broadcast shfls.
//  - final GEMM A rows at m=8..10 -> MoE output lands at g==2, the lanes
//    that already hold lin in cX2[0..2]; no lin shfls.
//
// Occupancy experiment (R10): honest pressure ~108 VGPR fits the 128-VGPR
// 4-wave budget. waves_per_eu(4,4) was pathological (R6: 64-cap + spill);
// __launch_bounds__(256,N) behaved sanely at N=3 (R2: 156 VGPR, no spill).
// Single variable vs R9: attribute -> __launch_bounds__(256,4), grid 1024.
// Falsifier: VGPR=64 or WRITE_SIZE >> 12,288 KB -> revert to (3,3).

__global__ __launch_bounds__(256, 4)
void moe_mfma9_kernel(
    const float* __restrict__ x,
    const float* __restrict__ W1,  const float* __restrict__ b1,
    const float* __restrict__ lng, const float* __restrict__ lnb,
    const float* __restrict__ W2,  const float* __restrict__ b2,
    const float* __restrict__ Wg1, const float* __restrict__ bg1,
    const float* __restrict__ Wg2, const float* __restrict__ bg2,
    const float* __restrict__ We1, const float* __restrict__ be1,
    const float* __restrict__ We2, const float* __restrict__ be2,
    const float* __restrict__ Wh,  const float* __restrict__ bh,
    const float* __restrict__ osc,
    float* __restrict__ out, int B, int niter)
{
    const int tid  = threadIdx.x;
    const int w    = tid >> 6;
    const int lane = tid & 63;
    const int c    = lane & 15;   // batch row within group / A-row m
    const int g    = lane >> 4;   // lane group 0..3

    const long long stride = (long long)gridDim.x * 128;   // 4 waves x 32 rows
    long long rowA = (long long)blockIdx.x * 128 + w * 32; // chain A base; B = +16

    // ---- prefetch iter 0 for both chains ----
    f32x4 pa0, pa1, pa2, pa3, pb0, pb1, pb2, pb3;
    {
        const long long pb_ = (rowA + 32 <= B) ? rowA : 0;
        const float* npA = x + (pb_ + c) * 64 + 8 * g;
        const float* npB = npA + 16 * 64;
        pa0 = *(const f32x4*)(npA);      pb0 = *(const f32x4*)(npB);
        pa1 = *(const f32x4*)(npA + 4);  pb1 = *(const f32x4*)(npB + 4);
        pa2 = *(const f32x4*)(npA + 32); pb2 = *(const f32x4*)(npB + 32);
        pa3 = *(const f32x4*)(npA + 36); pb3 = *(const f32x4*)(npB + 36);
    }

    // ================= one-time weight/bias fragment init =================
    // stage1 concat features f: [0,24)=W1, [24,40)=Wg1, [40,43)=Wh, pad to 48
    short8 a1[3][2];
#pragma unroll
    for (int t = 0; t < 3; ++t) {
        const int f = 16 * t + c;
#pragma unroll
        for (int s = 0; s < 2; ++s) {
            short8 r;
#pragma unroll
            for (int e = 0; e < 8; ++e) {
                const int k = 32 * s + 8 * g + e;
                float v = 0.0f;
                if (f < 24)      v = W1[k * 24 + f];
                else if (f < 40) v = Wg1[k * 16 + (f - 24)];
                else if (f < 43) v = Wh[k * 3 + (f - 40)];
                r[e] = (short)f2bf(v);
            }
            a1[t][s] = r;
        }
    }
    // W2 (lng folded into rows), K=24 padded to 32; bias b2' in k==24 slot
    short4v aw[2][2];
#pragma unroll
    for (int t = 0; t < 2; ++t) {
        const int f = 16 * t + c;
        float bfold = 0.0f;
        if (f < 24) {
            bfold = b2[f];
            for (int k = 0; k < 24; ++k) bfold += lnb[k] * W2[k * 24 + f];
        }
#pragma unroll
        for (int s = 0; s < 2; ++s) {
            short4v r;
#pragma unroll
            for (int e = 0; e < 4; ++e) {
                const int k = 16 * s + 4 * g + e;
                float v = (f < 24 && k < 24) ? lng[k] * W2[k * 24 + f] : 0.0f;
                if (s == 1 && g == 2 && e == 0) v = bfold;   // k==24 bias slot
                r[e] = (short)f2bf(v);
            }
            aw[t][s] = r;
        }
    }
    // experts hidden concat m=20*ei+j in [0,60), K=24 pad 32; be1 in k==24 slot
    short4v ae[4][2];
#pragma unroll
    for (int t = 0; t < 4; ++t) {
        const int f  = 16 * t + c;
        const int fc = (f < 60) ? f : 0;
        const int ei = fc / 20, j = fc % 20;
        const float bias = (f < 60) ? be1[f] : 0.0f;
#pragma unroll
        for (int s = 0; s < 2; ++s) {
            short4v r;
#pragma unroll
            for (int e = 0; e < 4; ++e) {
                const int k = 16 * s + 4 * g + e;
                float v = (f < 60 && k < 24) ? We1[(ei * 24 + k) * 20 + j] : 0.0f;
                if (s == 1 && g == 2 && e == 0) v = bias;    // k==24 bias slot
                r[e] = (short)f2bf(v);
            }
            ae[t][s] = r;
        }
    }
    // Final GEMM A at rows m=8..10 (o = c-8): k<60 -> We2*osc; k=60..62 -> be2*osc.
    short4v ao[4];
    {
        const int  o     = c - 8;
        const bool valid = (c >= 8 && c < 11);
        const int  oc    = valid ? o : 0;
        const float oscv = valid ? osc[oc] : 0.0f;
#pragma unroll
        for (int s = 0; s < 4; ++s) {
            short4v r;
#pragma unroll
            for (int e = 0; e < 4; ++e) {
                const int k = 16 * s + 4 * g + e;
                float v = 0.0f;
                if (valid) {
                    if (k < 60) {
                        const int ei = k / 20, j = k % 20;
                        v = We2[(ei * 20 + j) * 3 + oc] * oscv;
                    } else if (k < 63) {
                        v = be2[(k - 60) * 3 + oc] * oscv;
                    }
                }
                r[e] = (short)f2bf(v);
            }
            ao[s] = r;
        }
    }
    // gate Wg2 replicated across all 4 row-groups: row m holds Wg2[:, m%4] (m%4<3)
    short4v ag;
    {
        const int og = c & 3;
#pragma unroll
        for (int e = 0; e < 4; ++e) {
            const int k = 4 * g + e;
            float v = (og < 3) ? Wg2[k * 3 + og] : 0.0f;
            ag[e] = (short)f2bf(v);
        }
    }
    // stage1 biases
    float bs1[3][4];
#pragma unroll
    for (int t = 0; t < 3; ++t)
#pragma unroll
    for (int r = 0; r < 4; ++r) {
        const int m = 16 * t + 4 * g + r;
        float v = 0.0f;
        if (m < 24)      v = b1[m];
        else if (m < 40) v = bg1[m - 24];
        else if (m < 43) v = bh[m - 40];
        bs1[t][r] = v;
    }
    const float gb0 = bg2[0], gb1 = bg2[1], gb2 = bg2[2];
    const unsigned int ONEBF = 0x00003F80u;  // lo half = bf16(1.0)

    // ================= main loop: two interleaved 16-row chains =================
    for (int it = 0; it < niter; ++it) {
        const f32x4 qa0 = pa0, qa1 = pa1, qa2 = pa2, qa3 = pa3;
        const f32x4 qb0 = pb0, qb1 = pb1, qb2 = pb2, qb3 = pb3;
        const long long curA = rowA;
        const long long nrowA = rowA + stride;
        if (it + 1 < niter) {
            const long long pb_ = (nrowA + 32 <= B) ? nrowA : curA;
            const float* npA = x + (pb_ + c) * 64 + 8 * g;
            const float* npB = npA + 16 * 64;
            pa0 = *(const f32x4*)(npA);      pb0 = *(const f32x4*)(npB);
            pa1 = *(const f32x4*)(npA + 4);  pb1 = *(const f32x4*)(npB + 4);
            pa2 = *(const f32x4*)(npA + 32); pb2 = *(const f32x4*)(npB + 32);
            pa3 = *(const f32x4*)(npA + 36); pb3 = *(const f32x4*)(npB + 36);
        }

        // ---- x -> bf16 B fragments (both chains) ----
        const short8 bxA0 = mk8(cvt_pk(qa0[0],qa0[1]), cvt_pk(qa0[2],qa0[3]),
                                cvt_pk(qa1[0],qa1[1]), cvt_pk(qa1[2],qa1[3]));
        const short8 bxB0 = mk8(cvt_pk(qb0[0],qb0[1]), cvt_pk(qb0[2],qb0[3]),
                                cvt_pk(qb1[0],qb1[1]), cvt_pk(qb1[2],qb1[3]));
        const short8 bxA1 = mk8(cvt_pk(qa2[0],qa2[1]), cvt_pk(qa2[2],qa2[3]),
                                cvt_pk(qa3[0],qa3[1]), cvt_pk(qa3[2],qa3[3]));
        const short8 bxB1 = mk8(cvt_pk(qb2[0],qb2[1]), cvt_pk(qb2[2],qb2[3]),
                                cvt_pk(qb3[0],qb3[1]), cvt_pk(qb3[2],qb3[3]));

        // ---- stage 1 (interleaved) ----
        f32x4 cA0 = {bs1[0][0], bs1[0][1], bs1[0][2], bs1[0][3]};
        f32x4 cB0 = cA0;
        f32x4 cA1 = {bs1[1][0], bs1[1][1], bs1[1][2], bs1[1][3]};
        f32x4 cB1 = cA1;
        f32x4 cA2 = {bs1[2][0], bs1[2][1], bs1[2][2], bs1[2][3]};
        f32x4 cB2 = cA2;
        cA0 = MFMA32(a1[0][0], bxA0, cA0);  cB0 = MFMA32(a1[0][0], bxB0, cB0);
        cA0 = MFMA32(a1[0][1], bxA1, cA0);  cB0 = MFMA32(a1[0][1], bxB1, cB0);
        cA1 = MFMA32(a1[1][0], bxA0, cA1);  cB1 = MFMA32(a1[1][0], bxB0, cB1);
        cA1 = MFMA32(a1[1][1], bxA1, cA1);  cB1 = MFMA32(a1[1][1], bxB1, cB1);
        cA2 = MFMA32(a1[2][0], bxA0, cA2);  cB2 = MFMA32(a1[2][0], bxB0, cB2);
        cA2 = MFMA32(a1[2][1], bxA1, cA2);  cB2 = MFMA32(a1[2][1], bxB1, cB2);

        // ---- gate: tanh + lane^32 exchange; replicated-A MFMA -> per-lane logits ----
        const f32x4 tsA = (g < 2) ? cA2 : cA1;
        const f32x4 tsB = (g < 2) ? cB2 : cB1;
        const unsigned int gsA0 = cvt_pk(tanh_f(tsA[0]), tanh_f(tsA[1]));
        const unsigned int gsB0 = cvt_pk(tanh_f(tsB[0]), tanh_f(tsB[1]));
        const unsigned int gsA1 = cvt_pk(tanh_f(tsA[2]), tanh_f(tsA[3]));
        const unsigned int gsB1 = cvt_pk(tanh_f(tsB[2]), tanh_f(tsB[3]));
        const unsigned int grA0 = (unsigned int)__shfl_xor((int)gsA0, 32, 64);
        const unsigned int grB0 = (unsigned int)__shfl_xor((int)gsB0, 32, 64);
        const unsigned int grA1 = (unsigned int)__shfl_xor((int)gsA1, 32, 64);
        const unsigned int grB1 = (unsigned int)__shfl_xor((int)gsB1, 32, 64);
        f32x4 cgA = { gb0, gb1, gb2, 0.0f };
        f32x4 cgB = cgA;
        cgA = MFMA16(ag, mk4(grA0, grA1), cgA);
        cgB = MFMA16(ag, mk4(grB0, grB1), cgB);

        // ---- silu + LayerNorm (both chains; shared shfl cluster) ----
        const float hA00=silu_f(cA0[0]), hA01=silu_f(cA0[1]), hA02=silu_f(cA0[2]), hA03=silu_f(cA0[3]);
        const float hB00=silu_f(cB0[0]), hB01=silu_f(cB0[1]), hB02=silu_f(cB0[2]), hB03=silu_f(cB0[3]);
        const float hA10=silu_f(cA1[0]), hA11=silu_f(cA1[1]), hA12=silu_f(cA1[2]), hA13=silu_f(cA1[3]);
        const float hB10=silu_f(cB1[0]), hB11=silu_f(cB1[1]), hB12=silu_f(cB1[2]), hB13=silu_f(cB1[3]);
        float SA = hA00+hA01+hA02+hA03;
        float SB = hB00+hB01+hB02+hB03;
        float QA = hA00*hA00+hA01*hA01+hA02*hA02+hA03*hA03;
        float QB = hB00*hB00+hB01*hB01+hB02*hB02+hB03*hB03;
        if (g < 2) {
            SA += hA10+hA11+hA12+hA13;           SB += hB10+hB11+hB12+hB13;
            QA += hA10*hA10+hA11*hA11+hA12*hA12+hA13*hA13;
            QB += hB10*hB10+hB11*hB11+hB12*hB12+hB13*hB13;
        }
        SA += __shfl_xor(SA, 16, 64);  SB += __shfl_xor(SB, 16, 64);
        SA += __shfl_xor(SA, 32, 64);  SB += __shfl_xor(SB, 32, 64);
        QA += __shfl_xor(QA, 16, 64);  QB += __shfl_xor(QB, 16, 64);
        QA += __shfl_xor(QA, 32, 64);  QB += __shfl_xor(QB, 32, 64);
        const float muA = SA * (1.0f/24.0f), muB = SB * (1.0f/24.0f);
        float varA = QA * (1.0f/24.0f) - muA*muA; varA = fmaxf(varA, 0.0f);
        float varB = QB * (1.0f/24.0f) - muB*muB; varB = fmaxf(varB, 0.0f);
        const float invA = __builtin_amdgcn_rsqf(varA + 1e-5f);
        const float invB = __builtin_amdgcn_rsqf(varB + 1e-5f);

        const short4v BA0 = mk4(cvt_pk((hA00-muA)*invA, (hA01-muA)*invA),
                                cvt_pk((hA02-muA)*invA, (hA03-muA)*invA));
        const short4v BB0 = mk4(cvt_pk((hB00-muB)*invB, (hB01-muB)*invB),
                                cvt_pk((hB02-muB)*invB, (hB03-muB)*invB));
        const short4v BA1 = (g < 2) ? mk4(cvt_pk((hA10-muA)*invA, (hA11-muA)*invA),
                                          cvt_pk((hA12-muA)*invA, (hA13-muA)*invA))
                          : ((g == 2) ? mk4(ONEBF, 0u) : mk4(0u, 0u));
        const short4v BB1 = (g < 2) ? mk4(cvt_pk((hB10-muB)*invB, (hB11-muB)*invB),
                                          cvt_pk((hB12-muB)*invB, (hB13-muB)*invB))
                          : ((g == 2) ? mk4(ONEBF, 0u) : mk4(0u, 0u));

        // ---- stage 2 (interleaved) ----
        f32x4 dA0 = {0.f,0.f,0.f,0.f}, dB0 = {0.f,0.f,0.f,0.f};
        f32x4 dA1 = {0.f,0.f,0.f,0.f}, dB1 = {0.f,0.f,0.f,0.f};
        dA0 = MFMA16(aw[0][0], BA0, dA0);  dB0 = MFMA16(aw[0][0], BB0, dB0);
        dA0 = MFMA16(aw[0][1], BA1, dA0);  dB0 = MFMA16(aw[0][1], BB1, dB0);
        dA1 = MFMA16(aw[1][0], BA0, dA1);  dB1 = MFMA16(aw[1][0], BB0, dB1);
        dA1 = MFMA16(aw[1][1], BA1, dA1);  dB1 = MFMA16(aw[1][1], BB1, dB1);
        const float jA00=silu_f(dA0[0]), jA01=silu_f(dA0[1]), jA02=silu_f(dA0[2]), jA03=silu_f(dA0[3]);
        const float jB00=silu_f(dB0[0]), jB01=silu_f(dB0[1]), jB02=silu_f(dB0[2]), jB03=silu_f(dB0[3]);
        const float jA10=silu_f(dA1[0]), jA11=silu_f(dA1[1]), jA12=silu_f(dA1[2]), jA13=silu_f(dA1[3]);
        const float jB10=silu_f(dB1[0]), jB11=silu_f(dB1[1]), jB12=silu_f(dB1[2]), jB13=silu_f(dB1[3]);
        const short4v EA0 = mk4(cvt_pk(jA00,jA01), cvt_pk(jA02,jA03));
        const short4v EB0 = mk4(cvt_pk(jB00,jB01), cvt_pk(jB02,jB03));
        const short4v EA1 = (g < 2) ? mk4(cvt_pk(jA10,jA11), cvt_pk(jA12,jA13))
                          : ((g == 2) ? mk4(ONEBF, 0u) : mk4(0u, 0u));
        const short4v EB1 = (g < 2) ? mk4(cvt_pk(jB10,jB11), cvt_pk(jB12,jB13))
                          : ((g == 2) ? mk4(ONEBF, 0u) : mk4(0u, 0u));

        // ---- experts hidden (interleaved) ----
        f32x4 eA0={0.f,0.f,0.f,0.f}, eB0={0.f,0.f,0.f,0.f};
        f32x4 eA1={0.f,0.f,0.f,0.f}, eB1={0.f,0.f,0.f,0.f};
        f32x4 eA2={0.f,0.f,0.f,0.f}, eB2={0.f,0.f,0.f,0.f};
        f32x4 eA3={0.f,0.f,0.f,0.f}, eB3={0.f,0.f,0.f,0.f};
        eA0 = MFMA16(ae[0][0], EA0, eA0);  eB0 = MFMA16(ae[0][0], EB0, eB0);
        eA0 = MFMA16(ae[0][1], EA1, eA0);  eB0 = MFMA16(ae[0][1], EB1, eB0);
        eA1 = MFMA16(ae[1][0], EA0, eA1);  eB1 = MFMA16(ae[1][0], EB0, eB1);
        eA1 = MFMA16(ae[1][1], EA1, eA1);  eB1 = MFMA16(ae[1][1], EB1, eB1);
        eA2 = MFMA16(ae[2][0], EA0, eA2);  eB2 = MFMA16(ae[2][0], EB0, eB2);
        eA2 = MFMA16(ae[2][1], EA1, eA2);  eB2 = MFMA16(ae[2][1], EB1, eB2);
        eA3 = MFMA16(ae[3][0], EA0, eA3);  eB3 = MFMA16(ae[3][0], EB0, eB3);
        eA3 = MFMA16(ae[3][1], EA1, eA3);  eB3 = MFMA16(ae[3][1], EB1, eB3);

        // ---- softmax gate weights (per-lane logits; no shfls) ----
        const float xA0 = fexp2(cgA[0]*LOG2E), xA1 = fexp2(cgA[1]*LOG2E), xA2 = fexp2(cgA[2]*LOG2E);
        const float xB0 = fexp2(cgB[0]*LOG2E), xB1 = fexp2(cgB[1]*LOG2E), xB2 = fexp2(cgB[2]*LOG2E);
        const float rsA = frcp(xA0 + xA1 + xA2), rsB = frcp(xB0 + xB1 + xB2);
        const float gwA0 = xA0*rsA, gwA1 = xA1*rsA, gwA2 = xA2*rsA;
        const float gwB0 = xB0*rsB, gwB1 = xB1*rsB, gwB2 = xB2*rsB;

        // ---- final GEMM (interleaved): B = gw[expert(k)]*silu(eh[k]) ----
        const float gtA0 = gwA0, gtB0 = gwB0;
        const float gtA1 = (g == 0) ? gwA0 : gwA1, gtB1 = (g == 0) ? gwB0 : gwB1;
        const float gtA2 = (g < 2) ? gwA1 : gwA2,  gtB2 = (g < 2) ? gwB1 : gwB2;
        const float gtA3 = gwA2, gtB3 = gwB2;
        const short4v FA0 = mk4(cvt_pk(gtA0*silu_f(eA0[0]), gtA0*silu_f(eA0[1])),
                                cvt_pk(gtA0*silu_f(eA0[2]), gtA0*silu_f(eA0[3])));
        const short4v FB0 = mk4(cvt_pk(gtB0*silu_f(eB0[0]), gtB0*silu_f(eB0[1])),
                                cvt_pk(gtB0*silu_f(eB0[2]), gtB0*silu_f(eB0[3])));
        const short4v FA1 = mk4(cvt_pk(gtA1*silu_f(eA1[0]), gtA1*silu_f(eA1[1])),
                                cvt_pk(gtA1*silu_f(eA1[2]), gtA1*silu_f(eA1[3])));
        const short4v FB1 = mk4(cvt_pk(gtB1*silu_f(eB1[0]), gtB1*silu_f(eB1[1])),
                                cvt_pk(gtB1*silu_f(eB1[2]), gtB1*silu_f(eB1[3])));
        const short4v FA2 = mk4(cvt_pk(gtA2*silu_f(eA2[0]), gtA2*silu_f(eA2[1])),
                                cvt_pk(gtA2*silu_f(eA2[2]), gtA2*silu_f(eA2[3])));
        const short4v FB2 = mk4(cvt_pk(gtB2*silu_f(eB2[0]), gtB2*silu_f(eB2[1])),
                                cvt_pk(gtB2*silu_f(eB2[2]), gtB2*silu_f(eB2[3])));
        const short4v FA3 = (g == 3) ? mk4(cvt_pk(gwA0, gwA1), cvt_pk(gwA2, 0.0f))
                          : mk4(cvt_pk(gtA3*silu_f(eA3[0]), gtA3*silu_f(eA3[1])),
                                cvt_pk(gtA3*silu_f(eA3[2]), gtA3*silu_f(eA3[3])));
        const short4v FB3 = (g == 3) ? mk4(cvt_pk(gwB0, gwB1), cvt_pk(gwB2, 0.0f))
                          : mk4(cvt_pk(gtB3*silu_f(eB3[0]), gtB3*silu_f(eB3[1])),
                                cvt_pk(gtB3*silu_f(eB3[2]), gtB3*silu_f(eB3[3])));
        f32x4 coA = {0.f,0.f,0.f,0.f}, coB = {0.f,0.f,0.f,0.f};
        coA = MFMA16(ao[0], FA0, coA);  coB = MFMA16(ao[0], FB0, coB);
        coA = MFMA16(ao[1], FA1, coA);  coB = MFMA16(ao[1], FB1, coB);
        coA = MFMA16(ao[2], FA2, coA);  coB = MFMA16(ao[2], FB2, coB);
        coA = MFMA16(ao[3], FA3, coA);  coB = MFMA16(ao[3], FB3, coB);
        // co[r] at g==2 = gated+biased moe output o=r; lin lives in cX2[r] at g==2

        if (g == 2) {
            if (curA + c < B) {
                float* op = out + (curA + c) * 3;
                op[0] = cA2[0] + coA[0];
                op[1] = cA2[1] + coA[1];
                op[2] = cA2[2] + coA[2];
            }
            if (curA + 16 + c < B) {
                float* op = out + (curA + 16 + c) * 3;
                op[0] = cB2[0] + coB[0];
                op[1] = cB2[1] + coB[1];
                op[2] = cB2[2] + coB[2];
            }
        }

        rowA = nrowA;
    }
}

extern "C" void kernel_launch(void* const* d_in, const int* in_sizes, int n_in,
                              void* d_out, int out_size, void* d_ws, size_t ws_size,
                              hipStream_t stream) {
    const float* x   = (const float*)d_in[0];
    const float* W1  = (const float*)d_in[1];
    const float* b1  = (const float*)d_in[2];
    const float* lng = (const float*)d_in[3];
    const float* lnb = (const float*)d_in[4];
    const float* W2  = (const float*)d_in[5];
    const float* b2  = (const float*)d_in[6];
    const float* Wg1 = (const float*)d_in[7];
    const float* bg1 = (const float*)d_in[8];
    const float* Wg2 = (const float*)d_in[9];
    const float* bg2 = (const float*)d_in[10];
    const float* We1 = (const float*)d_in[11];
    const float* be1 = (const float*)d_in[12];
    const float* We2 = (const float*)d_in[13];
    const float* be2 = (const float*)d_in[14];
    const float* Wh  = (const float*)d_in[15];
    const float* bh  = (const float*)d_in[16];
    const float* osc = (const float*)d_in[17];
    float* out = (float*)d_out;

    const int B = in_sizes[0] / 64;
    const int G = 1024;                      // 4 blocks/CU at 4 waves/EU
    const long long per = (long long)G * 128;
    const int niter = (int)((B + per - 1) / per);
    moe_mfma9_kernel<<<dim3(G), dim3(256), 0, stream>>>(
        x, W1, b1, lng, lnb, W2, b2, Wg1, bg1, Wg2, bg2,
        We1, be1, We2, be2, Wh, bh, osc, out, B, niter);
}

// Round 11
// 84.190 us; speedup vs baseline: 2.0221x; 2.0221x over previous
//
#include <hip/hip_runtime.h>

typedef __attribute__((ext_vector_type(8))) short short8;
typedef __attribute__((ext_vector_type(4))) short short4v;
typedef __attribute__((ext_vector_type(4))) float f32x4;
typedef __attribute__((ext_vector_type(2))) unsigned int uint2v;
typedef __attribute__((ext_vector_type(4))) unsigned int uint4v;

#define LOG2E 1.44269504088896340736f

__device__ __forceinline__ float fexp2(float v){ return __builtin_amdgcn_exp2f(v); }
__device__ __forceinline__ float frcp(float v){ return __builtin_amdgcn_rcpf(v); }
__device__ __forceinline__ float silu_f(float v){ return v * frcp(1.0f + fexp2(-v*LOG2E)); }
__device__ __forceinline__ float tanh_f(float v){ return 2.0f*frcp(1.0f+fexp2(-2.0f*LOG2E*v)) - 1.0f; }

__device__ __forceinline__ unsigned short f2bf(float f){
    unsigned int u = __float_as_uint(f);
    u = (u + 0x7FFFu + ((u>>16)&1u)) >> 16;
    return (unsigned short)u;
}
// v_cvt_pk_bf16_f32: lo16 = bf16(a), hi16 = bf16(b)
__device__ __forceinline__ unsigned int cvt_pk(float a, float b){
    unsigned int r;
    asm("v_cvt_pk_bf16_f32 %0, %1, %2" : "=v"(r) : "v"(a), "v"(b));
    return r;
}
__device__ __forceinline__ short4v mk4(unsigned int u0, unsigned int u1){
    uint2v t; t[0] = u0; t[1] = u1;
    return __builtin_bit_cast(short4v, t);
}
__device__ __forceinline__ short8 mk8(unsigned int a, unsigned int b, unsigned int c, unsigned int d){
    uint4v t; t[0] = a; t[1] = b; t[2] = c; t[3] = d;
    return __builtin_bit_cast(short8, t);
}
__device__ __forceinline__ short8 pack2x4(short4v lo, short4v hi){
    return __builtin_shufflevector(lo, hi, 0,1,2,3,4,5,6,7);
}
__device__ __forceinline__ short4v lo4(short8 v){ return __builtin_shufflevector(v, v, 0,1,2,3); }
__device__ __forceinline__ short4v hi4(short8 v){ return __builtin_shufflevector(v, v, 4,5,6,7); }

#define MFMA32(a,b,c) __builtin_amdgcn_mfma_f32_16x16x32_bf16(a,b,c,0,0,0)
#define MFMA16(a,b,c) __builtin_amdgcn_mfma_f32_16x16x16bf16_1k(a,b,c,0,0,0)

// Fragment layouts (validated rounds 2-10):
//  A frag: m=lane&15,  k = KW*(lane>>4)+e   (KW=8 for x32, 4 for x16)
//  B frag: n=lane&15,  k = KW*(lane>>4)+e
//  C frag: n=lane&15,  m = 4*(lane>>4)+r
// Layout tricks (R9, kept): replicated gate A -> per-lane logits, no shfl;
//  final GEMM A at m=8..10 -> MoE output lands at g==2 beside lin.
//
// R11 structural change: persistent weight fragments live in LDS, not VGPRs.
//  - Identical for all waves in a block (lane-dependent only): wave 0 stages
//    WF[14][64] (16B/lane/slot; wave read = 64x16B contiguous -> conflict-free).
//  - Loop re-reads fragments per iteration (ds_read_b128 x14). The opaque-zero
//    zoff (asm "+v") makes addresses loop-variant -> LICM can't re-hoist the
//    fragments into registers (the R3/R4/R6/R10 spill trigger).
//  - Honest VGPR pressure drops ~108 -> ~80, so the unpinned allocator's
//    natural 64-84-VGPR / 6-8-wave target fits WITHOUT spilling. Contexts come
//    from waves (R9 proved contexts are the lever: 2->3 waves = -29%).

__global__ __launch_bounds__(256)
void moe_mfma10_kernel(
    const float* __restrict__ x,
    const float* __restrict__ W1,  const float* __restrict__ b1,
    const float* __restrict__ lng, const float* __restrict__ lnb,
    const float* __restrict__ W2,  const float* __restrict__ b2,
    const float* __restrict__ Wg1, const float* __restrict__ bg1,
    const float* __restrict__ Wg2, const float* __restrict__ bg2,
    const float* __restrict__ We1, const float* __restrict__ be1,
    const float* __restrict__ We2, const float* __restrict__ be2,
    const float* __restrict__ Wh,  const float* __restrict__ bh,
    const float* __restrict__ osc,
    float* __restrict__ out, int B, int niter)
{
    const int tid  = threadIdx.x;
    const int w    = tid >> 6;
    const int lane = tid & 63;
    const int c    = lane & 15;   // batch row within group / A-row m
    const int g    = lane >> 4;   // lane group 0..3

    __shared__ short8 WF[14][64];   // 14 KiB: slots x lanes, 16B each

    const int stride = (int)gridDim.x * 64;          // 4 waves x 16 rows
    int row0 = (int)blockIdx.x * 64 + w * 16;

    // ---- prefetch iter 0 ----
    f32x4 pf0, pf1, pf2, pf3;
    {
        int r = row0 + c; if (r >= B) r = B - 1; if (r < 0) r = 0;
        const float* xp = x + (size_t)r * 64 + 8 * g;
        pf0 = *(const f32x4*)(xp);
        pf1 = *(const f32x4*)(xp + 4);
        pf2 = *(const f32x4*)(xp + 32);
        pf3 = *(const f32x4*)(xp + 36);
    }

    // ================= wave 0 stages weight fragments into LDS =================
    if (w == 0) {
        // stage1 concat features f: [0,24)=W1, [24,40)=Wg1, [40,43)=Wh, pad 48
#pragma unroll
        for (int t = 0; t < 3; ++t) {
            const int f = 16 * t + c;
#pragma unroll
            for (int s = 0; s < 2; ++s) {
                short8 r;
#pragma unroll
                for (int e = 0; e < 8; ++e) {
                    const int k = 32 * s + 8 * g + e;
                    float v = 0.0f;
                    if (f < 24)      v = W1[k * 24 + f];
                    else if (f < 40) v = Wg1[k * 16 + (f - 24)];
                    else if (f < 43) v = Wh[k * 3 + (f - 40)];
                    r[e] = (short)f2bf(v);
                }
                WF[t * 2 + s][lane] = r;
            }
        }
        // W2 (lng folded), K=24 pad 32; b2' (lnb fold) in k==24 slot
#pragma unroll
        for (int t = 0; t < 2; ++t) {
            const int f = 16 * t + c;
            float bfold = 0.0f;
            if (f < 24) {
                bfold = b2[f];
                for (int k = 0; k < 24; ++k) bfold += lnb[k] * W2[k * 24 + f];
            }
            short4v h[2];
#pragma unroll
            for (int s = 0; s < 2; ++s) {
                short4v r;
#pragma unroll
                for (int e = 0; e < 4; ++e) {
                    const int k = 16 * s + 4 * g + e;
                    float v = (f < 24 && k < 24) ? lng[k] * W2[k * 24 + f] : 0.0f;
                    if (s == 1 && g == 2 && e == 0) v = bfold;
                    r[e] = (short)f2bf(v);
                }
                h[s] = r;
            }
            WF[6 + t][lane] = pack2x4(h[0], h[1]);
        }
        // experts hidden concat m in [0,60), K=24 pad 32; be1 in k==24 slot
#pragma unroll
        for (int t = 0; t < 4; ++t) {
            const int f  = 16 * t + c;
            const int fc = (f < 60) ? f : 0;
            const int ei = fc / 20, j = fc % 20;
            const float bias = (f < 60) ? be1[f] : 0.0f;
            short4v h[2];
#pragma unroll
            for (int s = 0; s < 2; ++s) {
                short4v r;
#pragma unroll
                for (int e = 0; e < 4; ++e) {
                    const int k = 16 * s + 4 * g + e;
                    float v = (f < 60 && k < 24) ? We1[(ei * 24 + k) * 20 + j] : 0.0f;
                    if (s == 1 && g == 2 && e == 0) v = bias;
                    r[e] = (short)f2bf(v);
                }
                h[s] = r;
            }
            WF[8 + t][lane] = pack2x4(h[0], h[1]);
        }
        // final GEMM A at rows m=8..10 (o=c-8): We2*osc, be2*osc in k=60..62
        {
            const int  o     = c - 8;
            const bool valid = (c >= 8 && c < 11);
            const int  oc    = valid ? o : 0;
            const float oscv = valid ? osc[oc] : 0.0f;
            short4v h[4];
#pragma unroll
            for (int s = 0; s < 4; ++s) {
                short4v r;
#pragma unroll
                for (int e = 0; e < 4; ++e) {
                    const int k = 16 * s + 4 * g + e;
                    float v = 0.0f;
                    if (valid) {
                        if (k < 60) {
                            const int ei = k / 20, j = k % 20;
                            v = We2[(ei * 20 + j) * 3 + oc] * oscv;
                        } else if (k < 63) {
                            v = be2[(k - 60) * 3 + oc] * oscv;
                        }
                    }
                    r[e] = (short)f2bf(v);
                }
                h[s] = r;
            }
            WF[12][lane] = pack2x4(h[0], h[1]);
            WF[13][lane] = pack2x4(h[2], h[3]);
        }
    }

    // ---- small persistent per-lane state (all waves) ----
    // gate Wg2 replicated across row-groups: row m holds Wg2[:, m%4]
    short4v ag;
    {
        const int og = c & 3;
#pragma unroll
        for (int e = 0; e < 4; ++e) {
            const int k = 4 * g + e;
            float v = (og < 3) ? Wg2[k * 3 + og] : 0.0f;
            ag[e] = (short)f2bf(v);
        }
    }
    float bs1[3][4];
#pragma unroll
    for (int t = 0; t < 3; ++t)
#pragma unroll
    for (int r = 0; r < 4; ++r) {
        const int m = 16 * t + 4 * g + r;
        float v = 0.0f;
        if (m < 24)      v = b1[m];
        else if (m < 40) v = bg1[m - 24];
        else if (m < 43) v = bh[m - 40];
        bs1[t][r] = v;
    }
    const float gb0 = bg2[0], gb1 = bg2[1], gb2 = bg2[2];
    const unsigned int ONEBF = 0x00003F80u;  // lo half = bf16(1.0)

    __syncthreads();   // WF ready; read-only hereafter (no barriers in loop)

    // ================= main loop: one 16-row chain per wave per iter =================
    for (int it = 0; it < niter; ++it) {
        if (row0 >= B) break;

        // opaque zero: LDS addresses become loop-variant -> no LICM re-hoist
        int zoff = 0;
        asm volatile("" : "+v"(zoff));
        const int li = lane + zoff;

        // ---- x -> bf16 B fragments (consumes pf before reloading it) ----
        const short8 bx0 = mk8(cvt_pk(pf0[0],pf0[1]), cvt_pk(pf0[2],pf0[3]),
                               cvt_pk(pf1[0],pf1[1]), cvt_pk(pf1[2],pf1[3]));
        const short8 bx1 = mk8(cvt_pk(pf2[0],pf2[1]), cvt_pk(pf2[2],pf2[3]),
                               cvt_pk(pf3[0],pf3[1]), cvt_pk(pf3[2],pf3[3]));

        const int cur  = row0;
        const int nrow = row0 + stride;
        if (it + 1 < niter && nrow < B) {
            int r = nrow + c; if (r >= B) r = B - 1;
            const float* np = x + (size_t)r * 64 + 8 * g;
            pf0 = *(const f32x4*)(np);
            pf1 = *(const f32x4*)(np + 4);
            pf2 = *(const f32x4*)(np + 32);
            pf3 = *(const f32x4*)(np + 36);
        }

        // ---- stage 1: 3 M-tiles x K=64 (A frags from LDS) ----
        const short8 A100 = WF[0][li], A101 = WF[1][li];
        const short8 A110 = WF[2][li], A111 = WF[3][li];
        const short8 A120 = WF[4][li], A121 = WF[5][li];
        f32x4 c0 = {bs1[0][0], bs1[0][1], bs1[0][2], bs1[0][3]};
        f32x4 c1 = {bs1[1][0], bs1[1][1], bs1[1][2], bs1[1][3]};
        f32x4 c2 = {bs1[2][0], bs1[2][1], bs1[2][2], bs1[2][3]};
        c0 = MFMA32(A100, bx0, c0); c0 = MFMA32(A101, bx1, c0);
        c1 = MFMA32(A110, bx0, c1); c1 = MFMA32(A111, bx1, c1);
        c2 = MFMA32(A120, bx0, c2); c2 = MFMA32(A121, bx1, c2);

        // ---- gate: tanh + lane^32 exchange; replicated-A -> per-lane logits ----
        const f32x4 ts = (g < 2) ? c2 : c1;
        const unsigned int gs0 = cvt_pk(tanh_f(ts[0]), tanh_f(ts[1]));
        const unsigned int gs1 = cvt_pk(tanh_f(ts[2]), tanh_f(ts[3]));
        const unsigned int gr0 = (unsigned int)__shfl_xor((int)gs0, 32, 64);
        const unsigned int gr1 = (unsigned int)__shfl_xor((int)gs1, 32, 64);
        f32x4 cg = { gb0, gb1, gb2, 0.0f };
        cg = MFMA16(ag, mk4(gr0, gr1), cg);

        // ---- silu + LayerNorm (lng/lnb folded into W2 frags) ----
        const float h00=silu_f(c0[0]), h01=silu_f(c0[1]), h02=silu_f(c0[2]), h03=silu_f(c0[3]);
        const float h10=silu_f(c1[0]), h11=silu_f(c1[1]), h12=silu_f(c1[2]), h13=silu_f(c1[3]);
        float S = h00+h01+h02+h03;
        float Q = h00*h00+h01*h01+h02*h02+h03*h03;
        if (g < 2) { S += h10+h11+h12+h13; Q += h10*h10+h11*h11+h12*h12+h13*h13; }
        S += __shfl_xor(S, 16, 64); S += __shfl_xor(S, 32, 64);
        Q += __shfl_xor(Q, 16, 64); Q += __shfl_xor(Q, 32, 64);
        const float mu = S * (1.0f/24.0f);
        float var = Q * (1.0f/24.0f) - mu*mu; var = fmaxf(var, 0.0f);
        const float inv = __builtin_amdgcn_rsqf(var + 1e-5f);

        const short4v B0 = mk4(cvt_pk((h00-mu)*inv, (h01-mu)*inv),
                               cvt_pk((h02-mu)*inv, (h03-mu)*inv));
        const short4v B1 = (g < 2) ? mk4(cvt_pk((h10-mu)*inv, (h11-mu)*inv),
                                         cvt_pk((h12-mu)*inv, (h13-mu)*inv))
                         : ((g == 2) ? mk4(ONEBF, 0u) : mk4(0u, 0u));

        // ---- stage 2 (A frags from LDS; bias rides k==24 slot) ----
        const short8 AWp0 = WF[6][li], AWp1 = WF[7][li];
        f32x4 d0 = {0.f,0.f,0.f,0.f}, d1 = {0.f,0.f,0.f,0.f};
        d0 = MFMA16(lo4(AWp0), B0, d0); d0 = MFMA16(hi4(AWp0), B1, d0);
        d1 = MFMA16(lo4(AWp1), B0, d1); d1 = MFMA16(hi4(AWp1), B1, d1);
        const float j00=silu_f(d0[0]), j01=silu_f(d0[1]), j02=silu_f(d0[2]), j03=silu_f(d0[3]);
        const float j10=silu_f(d1[0]), j11=silu_f(d1[1]), j12=silu_f(d1[2]), j13=silu_f(d1[3]);
        const short4v E0 = mk4(cvt_pk(j00,j01), cvt_pk(j02,j03));
        const short4v E1 = (g < 2) ? mk4(cvt_pk(j10,j11), cvt_pk(j12,j13))
                         : ((g == 2) ? mk4(ONEBF, 0u) : mk4(0u, 0u));

        // ---- experts hidden: 60-feature concat, 4 M-tiles ----
        const short8 AEp0 = WF[8][li],  AEp1 = WF[9][li];
        const short8 AEp2 = WF[10][li], AEp3 = WF[11][li];
        f32x4 e0={0.f,0.f,0.f,0.f}, e1={0.f,0.f,0.f,0.f};
        f32x4 e2={0.f,0.f,0.f,0.f}, e3={0.f,0.f,0.f,0.f};
        e0 = MFMA16(lo4(AEp0), E0, e0); e0 = MFMA16(hi4(AEp0), E1, e0);
        e1 = MFMA16(lo4(AEp1), E0, e1); e1 = MFMA16(hi4(AEp1), E1, e1);
        e2 = MFMA16(lo4(AEp2), E0, e2); e2 = MFMA16(hi4(AEp2), E1, e2);
        e3 = MFMA16(lo4(AEp3), E0, e3); e3 = MFMA16(hi4(AEp3), E1, e3);

        // ---- softmax gate weights (per-lane logits; tanh-bounded, no max-sub) ----
        const float x0 = fexp2(cg[0]*LOG2E), x1 = fexp2(cg[1]*LOG2E), x2 = fexp2(cg[2]*LOG2E);
        const float rs = frcp(x0 + x1 + x2);
        const float gw0 = x0*rs, gw1 = x1*rs, gw2 = x2*rs;

        // ---- final GEMM: B = gw[expert(k)]*silu(eh[k]) (k<60), gw vec in pads ----
        const float gt0 = gw0;
        const float gt1 = (g == 0) ? gw0 : gw1;
        const float gt2 = (g < 2) ? gw1 : gw2;
        const float gt3 = gw2;
        const short4v F0 = mk4(cvt_pk(gt0*silu_f(e0[0]), gt0*silu_f(e0[1])),
                               cvt_pk(gt0*silu_f(e0[2]), gt0*silu_f(e0[3])));
        const short4v F1 = mk4(cvt_pk(gt1*silu_f(e1[0]), gt1*silu_f(e1[1])),
                               cvt_pk(gt1*silu_f(e1[2]), gt1*silu_f(e1[3])));
        const short4v F2 = mk4(cvt_pk(gt2*silu_f(e2[0]), gt2*silu_f(e2[1])),
                               cvt_pk(gt2*silu_f(e2[2]), gt2*silu_f(e2[3])));
        const short4v F3 = (g == 3) ? mk4(cvt_pk(gw0, gw1), cvt_pk(gw2, 0.0f))
                         : mk4(cvt_pk(gt3*silu_f(e3[0]), gt3*silu_f(e3[1])),
                               cvt_pk(gt3*silu_f(e3[2]), gt3*silu_f(e3[3])));
        const short8 AOp0 = WF[12][li], AOp1 = WF[13][li];
        f32x4 co = {0.f,0.f,0.f,0.f};
        co = MFMA16(lo4(AOp0), F0, co); co = MFMA16(hi4(AOp0), F1, co);
        co = MFMA16(lo4(AOp1), F2, co); co = MFMA16(hi4(AOp1), F3, co);
        // co[r] at g==2 = gated+biased moe output o=r; lin lives in c2[r] at g==2

        if (g == 2 && cur + c < B) {
            float* op = out + (size_t)(cur + c) * 3;
            op[0] = c2[0] + co[0];
            op[1] = c2[1] + co[1];
            op[2] = c2[2] + co[2];
        }

        row0 = nrow;
    }
}

extern "C" void kernel_launch(void* const* d_in, const int* in_sizes, int n_in,
                              void* d_out, int out_size, void* d_ws, size_t ws_size,
                              hipStream_t stream) {
    const float* x   = (const float*)d_in[0];
    const float* W1  = (const float*)d_in[1];
    const float* b1  = (const float*)d_in[2];
    const float* lng = (const float*)d_in[3];
    const float* lnb = (const float*)d_in[4];
    const float* W2  = (const float*)d_in[5];
    const float* b2  = (const float*)d_in[6];
    const float* Wg1 = (const float*)d_in[7];
    const float* bg1 = (const float*)d_in[8];
    const float* Wg2 = (const float*)d_in[9];
    const float* bg2 = (const float*)d_in[10];
    const float* We1 = (const float*)d_in[11];
    const float* be1 = (const float*)d_in[12];
    const float* We2 = (const float*)d_in[13];
    const float* be2 = (const float*)d_in[14];
    const float* Wh  = (const float*)d_in[15];
    const float* bh  = (const float*)d_in[16];
    const float* osc = (const float*)d_in[17];
    float* out = (float*)d_out;

    const int B = in_sizes[0] / 64;
    const int G = 2048;                       // 8 blocks/CU target
    const long long per = (long long)G * 64;  // 64 rows/block/iter
    const int niter = (int)((B + per - 1) / per);
    moe_mfma10_kernel<<<dim3(G), dim3(256), 0, stream>>>(
        x, W1, b1, lng, lnb, W2, b2, Wg1, bg1, Wg2, bg2,
        We1, be1, We2, be2, Wh, bh, osc, out, B, niter);
}